// Round 13
// baseline (358.694 us; speedup 1.0000x reference)
//
#include <hip/hip_runtime.h>
#include <hip/hip_bf16.h>
#include <stdint.h>

#define B_SZ 4096
#define D_SZ 2048

typedef __attribute__((ext_vector_type(4))) float f32x4;
typedef __attribute__((ext_vector_type(8))) __bf16 bf16x8;
typedef __attribute__((ext_vector_type(4))) unsigned short u16x4;
typedef unsigned short u16;

static constexpr long BD = (long)B_SZ * D_SZ;   // 8388608
static constexpr long DD = (long)D_SZ * D_SZ;   // 4194304

__device__ __forceinline__ u16 f2bf(float f) {
  union { float f; unsigned int u; } c; c.f = f;
  unsigned int u = c.u;
  u = (u + 0x7fffu + ((u >> 16) & 1u)) >> 16;
  return (u16)u;
}

// ---------------------------------------------------------------- convert (all bf16)
__global__ __launch_bounds__(256) void k_convert(
    const float* __restrict__ x,  const float* __restrict__ wr,
    const float* __restrict__ wk, const float* __restrict__ wv,
    const float* __restrict__ wo,
    u16* __restrict__ Xb, u16* __restrict__ W3b, u16* __restrict__ Wob) {
  long i = ((long)blockIdx.x * 256 + threadIdx.x) * 4;
  const float* src; u16* dst; long so, dofs;
  if (i < BD)               { src = x;  so = i;            dst = Xb;  dofs = so; }
  else if (i < BD + DD)     { src = wr; so = i - BD;       dst = W3b; dofs = i - BD; }
  else if (i < BD + 2*DD)   { src = wk; so = i - BD - DD;  dst = W3b; dofs = i - BD; }
  else if (i < BD + 3*DD)   { src = wv; so = i - BD - 2*DD; dst = W3b; dofs = i - BD; }
  else                      { src = wo; so = i - BD - 3*DD; dst = Wob; dofs = so; }
  f32x4 v = *reinterpret_cast<const f32x4*>(src + so);
  u16x4 o;
  o[0] = f2bf(v[0]); o[1] = f2bf(v[1]); o[2] = f2bf(v[2]); o[3] = f2bf(v[3]);
  *reinterpret_cast<u16x4*>(dst + dofs) = o;
}

// ---------------------------------------------------------------- async global->LDS
__device__ __forceinline__ void gload16(const u16* g, const u16* l) {
  __builtin_amdgcn_global_load_lds(
      (const __attribute__((address_space(1))) unsigned int*)g,
      (__attribute__((address_space(3))) unsigned int*)l, 16, 0, 0);
}

#define FENCE asm volatile("" ::: "memory")
#define BAR do { FENCE; __builtin_amdgcn_s_barrier(); FENCE; } while (0)
#define VMC(n) asm volatile("s_waitcnt vmcnt(" #n ")" ::: "memory")

// ================================================================ fused bf16 rkv GEMM + WKV
// R9 structure with A-FRAGS DIRECT FROM GLOBAL (L2): A never touches LDS.
// Per-lane A-frag load: row wm*64+mi*16+(l&15), k-slot (l>>4)*8 -> 16x64B segments
// per instruction, L2-resident (A panel 0.5MB reused by 32 bn-blocks).
// LDS is B-only: 2 bufs x 3 x 64x64 bf16 = 48 KiB -> 2 blocks/CU.
// LDS traffic/K-tile-pair drops ~57% (reads) / 40% (writes) vs R9 -> below MFMA time.
// B DMA staging + swizzle + ping-pong schedule + epilogue: R9-verbatim.
__global__ __launch_bounds__(512, 4) void k_fused(
    const u16* __restrict__ A, const u16* __restrict__ W3,   // W3 = [Wr;Wk;Wv] rows
    const float* __restrict__ frac_n, const float* __restrict__ frac_d,
    const float* __restrict__ scale,
    const float* __restrict__ w_u, const float* __restrict__ w_w,
    float* __restrict__ o_nfn, float* __restrict__ o_nfd,
    float* __restrict__ o_ns,  u16* __restrict__ ab) {
  __shared__ __align__(16) u16 lds[24576];  // 48 KiB: buf p at p*12288 (u16)
  const int tid = threadIdx.x;
  const int l   = tid & 63;
  const int wid = tid >> 6;    // 0..7
  const int wm  = wid >> 2;    // 0..1  (M half: 64 rows)
  const int wn  = wid & 3;     // 0..3  (N quarter: 16 cols)
  const int bm = blockIdx.y, bn = blockIdx.x;
  const int K  = D_SZ;
  const int NT = K >> 6;       // 32

  // ---- A-frag global base: lane l -> row (l&15) of wave's 64-row half,
  //      k-slot (l>>4)*8 elements; per mi: +16 rows; per ks: +32 elements.
  const u16* Afrag = A + (long)(bm * 128 + wm * 64 + (l & 15)) * K + ((l >> 4) << 3);

  // ---- B DMA staging (inverse-swizzled global col, linear LDS dest) -- R9 geometry
  const int gcol = (((l & 7) ^ (l >> 3)) << 3);
  const int i0 = wid * 3;
  #define STAGE_B(t) do {                                                      \
    const long _ko = (long)(t) * 64;                                           \
    u16* _b = &lds[((t) & 1) * 12288];                                         \
    _Pragma("unroll")                                                          \
    for (int _c = 0; _c < 3; ++_c) {                                           \
      const int _i = i0 + _c, _j = _i >> 3, _rc = _i & 7;                      \
      const u16* _g = W3 + (long)_j * DD                                       \
                    + (long)(bn * 64 + _rc * 8 + (l >> 3)) * K + gcol + _ko;   \
      gload16(_g, _b + _j * 4096 + _rc * 512);                                 \
    }                                                                          \
  } while (0)

  // ---- B read-side addressing (swizzled; rows = 128 B) -- R9 formula
  const int rby  = (l & 15) * 128;
  const int obx0 = ((l >> 4) * 16) ^ ((l & 7) << 4);
  const int lo0  = (rby + obx0) >> 1;      // u16 index
  const int lo1  = lo0 ^ 32;               // ks=1 (byte ^ 64)

  f32x4 acc[3][4] = {};

  auto COMPUTE = [&](int p, int t) {
    const int base = p * 12288;
    const u16* Ag = Afrag + (long)t * 64;
#pragma unroll
    for (int ks = 0; ks < 2; ++ks) {
      const int lo = ks ? lo1 : lo0;
      bf16x8 af[4], fb[3];
#pragma unroll
      for (int mi = 0; mi < 4; ++mi)
        af[mi] = *reinterpret_cast<const bf16x8*>(Ag + (long)mi * 16 * K + ks * 32);
#pragma unroll
      for (int j = 0; j < 3; ++j)
        fb[j] = *reinterpret_cast<const bf16x8*>(
            &lds[base + j * 4096 + wn * 1024 + lo]);
      __builtin_amdgcn_s_setprio(1);
#pragma unroll
      for (int j = 0; j < 3; ++j)
#pragma unroll
        for (int mi = 0; mi < 4; ++mi)
          acc[j][mi] = __builtin_amdgcn_mfma_f32_16x16x32_bf16(
              af[mi], fb[j], acc[j][mi], 0, 0, 0);
      __builtin_amdgcn_s_setprio(0);
    }
  };

  // ---- prologue + R5/R9-proven ping-pong
  STAGE_B(0);
  VMC(0); BAR;
  for (int t = 0; t < NT - 1; ++t) {
    STAGE_B(t + 1);
    COMPUTE(t & 1, t);
    VMC(0); BAR;       // proves B(t+1); A-frag loads are reg-consumed (auto-waited)
  }
  COMPUTE((NT - 1) & 1, NT - 1);
  #undef STAGE_B

  // ---- fused WKV epilogue (fp32) -- R9-verbatim
  const long row0 = (long)bm * 128 + wm * 64 + (l >> 4) * 4;
  const long gc   = (long)bn * 64 + wn * 16 + (l & 15);
  const float wuv = w_u[gc];
  const float wwv = w_w[gc];
#pragma unroll
  for (int mi = 0; mi < 4; ++mi)
#pragma unroll
    for (int r = 0; r < 4; ++r) {
      const long gr  = row0 + mi * 16 + r;
      const long idx = gr * D_SZ + gc;
      const float rr = acc[0][mi][r];
      const float kk = acc[1][mi][r];
      const float vv = acc[2][mi][r];
      const float n  = frac_n[idx];
      const float dn = frac_d[idx];
      const float s  = scale[idx];

      const float rt  = 1.0f / (1.0f + __expf(-rr));
      const float ss  = fmaxf(s, wuv + kk);
      const float cm  = __expf(s - ss);
      const float am  = __expf(wuv + kk - ss);
      const float fnt = cm * n + am * vv;
      const float fdt = cm * dn + am;

      const float ns2 = fmaxf(s + wwv, kk);
      const float ncm = __expf(s + wwv - ns2);
      const float nam = __expf(kk - ns2);

      o_nfn[idx] = ncm * n + nam * vv;
      o_nfd[idx] = ncm * dn + nam;
      o_ns[idx]  = ns2;
      ab[idx]    = f2bf(rt * (fnt / fdt));
    }
}

// ================================================================ 128x128 bf16 GEMM (out-proj)
// EXACT R9/R5-proven version.
template <bool OUT_BF16>
__global__ __launch_bounds__(256, 4) void k_gemm128(
    const u16* __restrict__ A, const u16* __restrict__ Bm,
    void* __restrict__ C, int M, int N, int K) {
  __shared__ __align__(16) u16 lds[32768];  // 64 KiB
  const int tid = threadIdx.x;
  const int l   = tid & 63;
  const int w   = tid >> 6;
  const int wm  = w >> 1, wn = w & 1;
  const int bm = blockIdx.y, bn = blockIdx.x;
  const int NT = K >> 6;

  const int gcol  = (((l & 7) ^ (l >> 3)) << 3);
  const int grow  = w * 32 + (l >> 3);
  const u16* Abase = A  + (long)(bm * 128 + grow) * K + gcol;
  const u16* Bbase = Bm + (long)(bn * 128 + grow) * K + gcol;
  const int sdst = w * 2048;

  #define STAGE(t) do {                                              \
    const long _ko = (long)(t) * 64;                                 \
    u16* _da = &lds[((t) & 1) * 16384 + sdst];                       \
    u16* _db = _da + 8192;                                           \
    _Pragma("unroll")                                                \
    for (int _c = 0; _c < 4; ++_c) {                                 \
      gload16(Abase + (long)_c * 8 * K + _ko, _da + _c * 512);       \
      gload16(Bbase + (long)_c * 8 * K + _ko, _db + _c * 512);       \
    }                                                                \
  } while (0)

  const int rby  = (l & 15) * 128;
  const int obx0 = ((l >> 4) * 16) ^ ((l & 7) << 4);
  const int lo0  = (rby + obx0) >> 1;
  const int lo1  = lo0 ^ 32;

  f32x4 acc[4][4] = {};

  auto COMPUTE = [&](int p) {
#pragma unroll
    for (int ks = 0; ks < 2; ++ks) {
      const int lo = ks ? lo1 : lo0;
      bf16x8 af[4], bf[4];
#pragma unroll
      for (int mi = 0; mi < 4; ++mi)
        af[mi] = *reinterpret_cast<const bf16x8*>(
            &lds[p * 16384 + (wm * 4 + mi) * 1024 + lo]);
#pragma unroll
      for (int ni = 0; ni < 4; ++ni)
        bf[ni] = *reinterpret_cast<const bf16x8*>(
            &lds[p * 16384 + 8192 + (wn * 4 + ni) * 1024 + lo]);
      __builtin_amdgcn_s_setprio(1);
#pragma unroll
      for (int mi = 0; mi < 4; ++mi)
#pragma unroll
        for (int ni = 0; ni < 4; ++ni)
          acc[mi][ni] = __builtin_amdgcn_mfma_f32_16x16x32_bf16(
              af[mi], bf[ni], acc[mi][ni], 0, 0, 0);
      __builtin_amdgcn_s_setprio(0);
    }
  };

  STAGE(0);
  VMC(0); BAR;
  for (int t = 0; t < NT - 1; ++t) {
    STAGE(t + 1);
    COMPUTE(t & 1);
    VMC(0); BAR;
  }
  COMPUTE((NT - 1) & 1);
  #undef STAGE

  const int rb = (l >> 4) * 4, cb = l & 15;
  const long Crow0 = (long)bm * 128 + wm * 64 + rb;
  const long Ccol0 = (long)bn * 128 + wn * 64 + cb;
#pragma unroll
  for (int mi = 0; mi < 4; ++mi)
#pragma unroll
    for (int ni = 0; ni < 4; ++ni)
#pragma unroll
      for (int r = 0; r < 4; ++r) {
        const long gr = Crow0 + mi * 16 + r;
        const long gc = Ccol0 + ni * 16;
        if constexpr (OUT_BF16)
          ((u16*)C)[gr * N + gc] = f2bf(acc[mi][ni][r]);
        else
          ((float*)C)[gr * N + gc] = acc[mi][ni][r];
      }
}

// ---------------------------------------------------------------- launch
extern "C" void kernel_launch(void* const* d_in, const int* in_sizes, int n_in,
                              void* d_out, int out_size, void* d_ws, size_t ws_size,
                              hipStream_t stream) {
  const float* x      = (const float*)d_in[0];
  const float* frac_n = (const float*)d_in[1];
  const float* frac_d = (const float*)d_in[2];
  const float* scale  = (const float*)d_in[3];
  const float* wr     = (const float*)d_in[4];
  const float* wk     = (const float*)d_in[5];
  const float* wv     = (const float*)d_in[6];
  const float* wo     = (const float*)d_in[7];
  const float* wu     = (const float*)d_in[8];
  const float* ww     = (const float*)d_in[9];
  float* out = (float*)d_out;

  u16* Xb   = (u16*)d_ws;        // BD
  u16* W3b  = Xb + BD;           // 3*DD  (w_r | w_k | w_v rows)
  u16* Wob  = W3b + 3 * DD;      // DD
  u16* ab   = Wob + DD;          // BD

  // 1) fp32 -> bf16 conversions (R9-exact)
  {
    const long total = BD + 4 * DD;             // 25165824
    const int blocks = (int)(total / 4 / 256);  // 24576 exact
    k_convert<<<blocks, 256, 0, stream>>>(x, wr, wk, wv, wo, Xb, W3b, Wob);
  }
  // 2) fused rkv GEMM + WKV elementwise (A-frags direct from L2, B via LDS)
  k_fused<<<dim3(D_SZ / 64, B_SZ / 128), 512, 0, stream>>>(
      Xb, W3b, frac_n, frac_d, scale, wu, ww,
      out + BD, out + 2 * BD, out + 3 * BD, ab);
  // 3) output = a @ Wo^T -> d_out[0:BD] fp32 (R9-exact)
  k_gemm128<false><<<dim3(D_SZ / 128, B_SZ / 128), 256, 0, stream>>>(
      ab, Wob, out, B_SZ, D_SZ, D_SZ);
}

// Round 14
// 200.243 us; speedup vs baseline: 1.7913x; 1.7913x over previous
//
#include <hip/hip_runtime.h>
#include <hip/hip_bf16.h>
#include <stdint.h>

#define B_SZ 4096
#define D_SZ 2048

typedef __attribute__((ext_vector_type(4))) float f32x4;
typedef __attribute__((ext_vector_type(8))) __bf16 bf16x8;
typedef __attribute__((ext_vector_type(4))) unsigned short u16x4;
typedef unsigned short u16;

static constexpr long BD = (long)B_SZ * D_SZ;   // 8388608
static constexpr long DD = (long)D_SZ * D_SZ;   // 4194304

__device__ __forceinline__ u16 f2bf(float f) {
  union { float f; unsigned int u; } c; c.f = f;
  unsigned int u = c.u;
  u = (u + 0x7fffu + ((u >> 16) & 1u)) >> 16;
  return (u16)u;
}

// ---------------------------------------------------------------- convert (all bf16)
__global__ __launch_bounds__(256) void k_convert(
    const float* __restrict__ x,  const float* __restrict__ wr,
    const float* __restrict__ wk, const float* __restrict__ wv,
    const float* __restrict__ wo,
    u16* __restrict__ Xb, u16* __restrict__ W3b, u16* __restrict__ Wob) {
  long i = ((long)blockIdx.x * 256 + threadIdx.x) * 4;
  const float* src; u16* dst; long so, dofs;
  if (i < BD)               { src = x;  so = i;            dst = Xb;  dofs = so; }
  else if (i < BD + DD)     { src = wr; so = i - BD;       dst = W3b; dofs = i - BD; }
  else if (i < BD + 2*DD)   { src = wk; so = i - BD - DD;  dst = W3b; dofs = i - BD; }
  else if (i < BD + 3*DD)   { src = wv; so = i - BD - 2*DD; dst = W3b; dofs = i - BD; }
  else                      { src = wo; so = i - BD - 3*DD; dst = Wob; dofs = so; }
  f32x4 v = *reinterpret_cast<const f32x4*>(src + so);
  u16x4 o;
  o[0] = f2bf(v[0]); o[1] = f2bf(v[1]); o[2] = f2bf(v[2]); o[3] = f2bf(v[3]);
  *reinterpret_cast<u16x4*>(dst + dofs) = o;
}

// ---------------------------------------------------------------- async global->LDS
__device__ __forceinline__ void gload16(const u16* g, const u16* l) {
  __builtin_amdgcn_global_load_lds(
      (const __attribute__((address_space(1))) unsigned int*)g,
      (__attribute__((address_space(3))) unsigned int*)l, 16, 0, 0);
}

#define FENCE asm volatile("" ::: "memory")
#define BAR do { FENCE; __builtin_amdgcn_s_barrier(); FENCE; } while (0)
#define VMC(n) asm volatile("s_waitcnt vmcnt(" #n ")" ::: "memory")

// ================================================================ fused bf16 rkv GEMM + WKV
// R9 structure (proven 140.3 us) with ONE change: COMPUTE hoists ALL fragment
// loads (af[2][4], fb[2][3] = 14 b128) ahead of the 24-MFMA cluster, so the
// read issue-stream (14 x 12cy = 168cy) covers ds_read latency (~120cy) by
// construction instead of relying on the compiler's 56-VGPR tight interleave.
__global__ __launch_bounds__(512, 4) void k_fused(
    const u16* __restrict__ A, const u16* __restrict__ W3,   // W3 = [Wr;Wk;Wv] rows
    const float* __restrict__ frac_n, const float* __restrict__ frac_d,
    const float* __restrict__ scale,
    const float* __restrict__ w_u, const float* __restrict__ w_w,
    float* __restrict__ o_nfn, float* __restrict__ o_nfd,
    float* __restrict__ o_ns,  u16* __restrict__ ab) {
  __shared__ __align__(16) u16 lds[40960];  // 80 KiB: buf p at p*20480 (u16)
  const int tid = threadIdx.x;
  const int l   = tid & 63;
  const int wid = tid >> 6;    // 0..7
  const int wm  = wid >> 2;    // 0..1  (M half: 64 rows)
  const int wn  = wid & 3;     // 0..3  (N quarter: 16 cols)
  const int bm = blockIdx.y, bn = blockIdx.x;
  const int K  = D_SZ;
  const int NT = K >> 6;       // 32

  const int gcol = (((l & 7) ^ (l >> 3)) << 3);
  const u16* Abase = A + (long)(bm * 128 + wid * 16 + (l >> 3)) * K + gcol;
  const int i0 = wid * 3;

  #define STAGE(t) do {                                                        \
    const long _ko = (long)(t) * 64;                                           \
    u16* _b = &lds[((t) & 1) * 20480];                                         \
    gload16(Abase + _ko,                _b + wid * 1024);                      \
    gload16(Abase + 8 * (long)K + _ko,  _b + wid * 1024 + 512);                \
    _Pragma("unroll")                                                          \
    for (int _c = 0; _c < 3; ++_c) {                                           \
      const int _i = i0 + _c, _j = _i >> 3, _rc = _i & 7;                      \
      const u16* _g = W3 + (long)_j * DD                                       \
                    + (long)(bn * 64 + _rc * 8 + (l >> 3)) * K + gcol + _ko;   \
      gload16(_g, _b + 8192 + _j * 4096 + _rc * 512);                          \
    }                                                                          \
  } while (0)

  const int rby  = (l & 15) * 128;
  const int obx0 = ((l >> 4) * 16) ^ ((l & 7) << 4);
  const int lo0  = (rby + obx0) >> 1;      // u16 index
  const int lo1  = lo0 ^ 32;               // ks=1 (byte ^ 64)

  f32x4 acc[3][4] = {};

  auto COMPUTE = [&](int p) {
    const int base = p * 20480;
    bf16x8 af[2][4], fb[2][3];
    // ---- hoisted load burst: 14 x ds_read_b128 ----
#pragma unroll
    for (int ks = 0; ks < 2; ++ks) {
      const int lo = ks ? lo1 : lo0;
#pragma unroll
      for (int mi = 0; mi < 4; ++mi)
        af[ks][mi] = *reinterpret_cast<const bf16x8*>(
            &lds[base + wm * 4096 + mi * 1024 + lo]);
#pragma unroll
      for (int j = 0; j < 3; ++j)
        fb[ks][j] = *reinterpret_cast<const bf16x8*>(
            &lds[base + 8192 + j * 4096 + wn * 1024 + lo]);
    }
    // ---- MFMA cluster ----
    __builtin_amdgcn_s_setprio(1);
#pragma unroll
    for (int ks = 0; ks < 2; ++ks)
#pragma unroll
      for (int j = 0; j < 3; ++j)
#pragma unroll
        for (int mi = 0; mi < 4; ++mi)
          acc[j][mi] = __builtin_amdgcn_mfma_f32_16x16x32_bf16(
              af[ks][mi], fb[ks][j], acc[j][mi], 0, 0, 0);
    __builtin_amdgcn_s_setprio(0);
  };

  STAGE(0);
  VMC(0); BAR;
  for (int t = 0; t < NT - 1; ++t) {
    STAGE(t + 1);
    COMPUTE(t & 1);
    VMC(0); BAR;
  }
  COMPUTE((NT - 1) & 1);
  #undef STAGE

  // ---- fused WKV epilogue (fp32) -- R9-verbatim
  const long row0 = (long)bm * 128 + wm * 64 + (l >> 4) * 4;
  const long gc   = (long)bn * 64 + wn * 16 + (l & 15);
  const float wuv = w_u[gc];
  const float wwv = w_w[gc];
#pragma unroll
  for (int mi = 0; mi < 4; ++mi)
#pragma unroll
    for (int r = 0; r < 4; ++r) {
      const long gr  = row0 + mi * 16 + r;
      const long idx = gr * D_SZ + gc;
      const float rr = acc[0][mi][r];
      const float kk = acc[1][mi][r];
      const float vv = acc[2][mi][r];
      const float n  = frac_n[idx];
      const float dn = frac_d[idx];
      const float s  = scale[idx];

      const float rt  = 1.0f / (1.0f + __expf(-rr));
      const float ss  = fmaxf(s, wuv + kk);
      const float cm  = __expf(s - ss);
      const float am  = __expf(wuv + kk - ss);
      const float fnt = cm * n + am * vv;
      const float fdt = cm * dn + am;

      const float ns2 = fmaxf(s + wwv, kk);
      const float ncm = __expf(s + wwv - ns2);
      const float nam = __expf(kk - ns2);

      o_nfn[idx] = ncm * n + nam * vv;
      o_nfd[idx] = ncm * dn + nam;
      o_ns[idx]  = ns2;
      ab[idx]    = f2bf(rt * (fnt / fdt));
    }
}

// ================================================================ 128x128 bf16 GEMM (out-proj)
// R9 structure + the same hoisted-fragment COMPUTE (16 b128 then 32 MFMA).
template <bool OUT_BF16>
__global__ __launch_bounds__(256, 4) void k_gemm128(
    const u16* __restrict__ A, const u16* __restrict__ Bm,
    void* __restrict__ C, int M, int N, int K) {
  __shared__ __align__(16) u16 lds[32768];  // 64 KiB
  const int tid = threadIdx.x;
  const int l   = tid & 63;
  const int w   = tid >> 6;
  const int wm  = w >> 1, wn = w & 1;
  const int bm = blockIdx.y, bn = blockIdx.x;
  const int NT = K >> 6;

  const int gcol  = (((l & 7) ^ (l >> 3)) << 3);
  const int grow  = w * 32 + (l >> 3);
  const u16* Abase = A  + (long)(bm * 128 + grow) * K + gcol;
  const u16* Bbase = Bm + (long)(bn * 128 + grow) * K + gcol;
  const int sdst = w * 2048;

  #define STAGE(t) do {                                              \
    const long _ko = (long)(t) * 64;                                 \
    u16* _da = &lds[((t) & 1) * 16384 + sdst];                       \
    u16* _db = _da + 8192;                                           \
    _Pragma("unroll")                                                \
    for (int _c = 0; _c < 4; ++_c) {                                 \
      gload16(Abase + (long)_c * 8 * K + _ko, _da + _c * 512);       \
      gload16(Bbase + (long)_c * 8 * K + _ko, _db + _c * 512);       \
    }                                                                \
  } while (0)

  const int rby  = (l & 15) * 128;
  const int obx0 = ((l >> 4) * 16) ^ ((l & 7) << 4);
  const int lo0  = (rby + obx0) >> 1;
  const int lo1  = lo0 ^ 32;

  f32x4 acc[4][4] = {};

  auto COMPUTE = [&](int p) {
    bf16x8 af[2][4], bf[2][4];
#pragma unroll
    for (int ks = 0; ks < 2; ++ks) {
      const int lo = ks ? lo1 : lo0;
#pragma unroll
      for (int mi = 0; mi < 4; ++mi)
        af[ks][mi] = *reinterpret_cast<const bf16x8*>(
            &lds[p * 16384 + (wm * 4 + mi) * 1024 + lo]);
#pragma unroll
      for (int ni = 0; ni < 4; ++ni)
        bf[ks][ni] = *reinterpret_cast<const bf16x8*>(
            &lds[p * 16384 + 8192 + (wn * 4 + ni) * 1024 + lo]);
    }
    __builtin_amdgcn_s_setprio(1);
#pragma unroll
    for (int ks = 0; ks < 2; ++ks)
#pragma unroll
      for (int mi = 0; mi < 4; ++mi)
#pragma unroll
        for (int ni = 0; ni < 4; ++ni)
          acc[mi][ni] = __builtin_amdgcn_mfma_f32_16x16x32_bf16(
              af[ks][mi], bf[ks][ni], acc[mi][ni], 0, 0, 0);
    __builtin_amdgcn_s_setprio(0);
  };

  STAGE(0);
  VMC(0); BAR;
  for (int t = 0; t < NT - 1; ++t) {
    STAGE(t + 1);
    COMPUTE(t & 1);
    VMC(0); BAR;
  }
  COMPUTE((NT - 1) & 1);
  #undef STAGE

  const int rb = (l >> 4) * 4, cb = l & 15;
  const long Crow0 = (long)bm * 128 + wm * 64 + rb;
  const long Ccol0 = (long)bn * 128 + wn * 64 + cb;
#pragma unroll
  for (int mi = 0; mi < 4; ++mi)
#pragma unroll
    for (int ni = 0; ni < 4; ++ni)
#pragma unroll
      for (int r = 0; r < 4; ++r) {
        const long gr = Crow0 + mi * 16 + r;
        const long gc = Ccol0 + ni * 16;
        if constexpr (OUT_BF16)
          ((u16*)C)[gr * N + gc] = f2bf(acc[mi][ni][r]);
        else
          ((float*)C)[gr * N + gc] = acc[mi][ni][r];
      }
}

// ---------------------------------------------------------------- launch
extern "C" void kernel_launch(void* const* d_in, const int* in_sizes, int n_in,
                              void* d_out, int out_size, void* d_ws, size_t ws_size,
                              hipStream_t stream) {
  const float* x      = (const float*)d_in[0];
  const float* frac_n = (const float*)d_in[1];
  const float* frac_d = (const float*)d_in[2];
  const float* scale  = (const float*)d_in[3];
  const float* wr     = (const float*)d_in[4];
  const float* wk     = (const float*)d_in[5];
  const float* wv     = (const float*)d_in[6];
  const float* wo     = (const float*)d_in[7];
  const float* wu     = (const float*)d_in[8];
  const float* ww     = (const float*)d_in[9];
  float* out = (float*)d_out;

  u16* Xb   = (u16*)d_ws;        // BD
  u16* W3b  = Xb + BD;           // 3*DD  (w_r | w_k | w_v rows)
  u16* Wob  = W3b + 3 * DD;      // DD
  u16* ab   = Wob + DD;          // BD

  // 1) fp32 -> bf16 conversions
  {
    const long total = BD + 4 * DD;             // 25165824
    const int blocks = (int)(total / 4 / 256);  // 24576 exact
    k_convert<<<blocks, 256, 0, stream>>>(x, wr, wk, wv, wo, Xb, W3b, Wob);
  }
  // 2) fused rkv GEMM + WKV elementwise
  k_fused<<<dim3(D_SZ / 64, B_SZ / 128), 512, 0, stream>>>(
      Xb, W3b, frac_n, frac_d, scale, wu, ww,
      out + BD, out + 2 * BD, out + 3 * BD, ab);
  // 3) output = a @ Wo^T -> d_out[0:BD] fp32
  k_gemm128<false><<<dim3(D_SZ / 128, B_SZ / 128), 256, 0, stream>>>(
      ab, Wob, out, B_SZ, D_SZ, D_SZ);
}